// Round 6
// baseline (3242.257 us; speedup 1.0000x reference)
//
#include <hip/hip_runtime.h>
#include <hip/hip_bf16.h>

#define Bv 8
#define Tv 16
#define Hv 64
#define Wv 64
#define Cv 16
#define HID 64
#define PH 66   // spatially padded (1-px halo)

typedef short short8 __attribute__((ext_vector_type(8)));
typedef float f32x4 __attribute__((ext_vector_type(4)));
typedef unsigned short u16x8 __attribute__((ext_vector_type(8)));

__device__ __forceinline__ unsigned short f2bf(float x) {
  union { float f; unsigned int u; } v; v.f = x;
  unsigned int r = v.u + 0x7FFF + ((v.u >> 16) & 1);   // RNE
  return (unsigned short)(r >> 16);
}
__device__ __forceinline__ float sigmoid_f(float x) {
  return 1.f / (1.f + __expf(-x));
}
__device__ __forceinline__ float tanh_f(float x) {
  float e = __expf(2.f * x);
  return 1.f - 2.f / (e + 1.f);
}

// ---- weight re-layouts: fp32 [3,3,CI,256] -> bf16 lane-contiguous chunks.
// Chunk cc (16KB): [wn(4)][g(4)][lane(64)][e(8)]; lane l=(kg*16+r) holds
// B[k=kg*8+e][col' = wn*64+g*16+r], orig col = g*64 + wn*16 + r.
__global__ void relayout_w0(const float* __restrict__ W0, unsigned short* __restrict__ out) {
  int o = blockIdx.x * 256 + threadIdx.x;            // 27*8192 = 221184
  if (o >= 27 * 8192) return;
  int cc = o >> 13, t = o & 8191;
  int wn = t >> 11, t2 = t & 2047;
  int g = t2 >> 9, t3 = t2 & 511;
  int l = t3 >> 3, e = t3 & 7;
  int kg = l >> 4, r = l & 15;
  int k = kg * 8 + e;
  int col = g * 64 + wn * 16 + r;
  int tap = cc / 3, cgi = cc - tap * 3;
  int p = cgi * 32 + k;                              // padded ci: 0..15 x, 16..31 pad, 32..95 h
  float v = 0.f;
  if (p < 16)        v = W0[(size_t)(tap * 80 + p) * 256 + col];
  else if (p >= 32)  v = W0[(size_t)(tap * 80 + (p - 16)) * 256 + col];
  out[o] = f2bf(v);
}
__global__ void relayout_w1(const float* __restrict__ W1, unsigned short* __restrict__ out) {
  int o = blockIdx.x * 256 + threadIdx.x;            // 36*8192 = 294912
  if (o >= 36 * 8192) return;
  int cc = o >> 13, t = o & 8191;
  int wn = t >> 11, t2 = t & 2047;
  int g = t2 >> 9, t3 = t2 & 511;
  int l = t3 >> 3, e = t3 & 7;
  int kg = l >> 4, r = l & 15;
  int k = kg * 8 + e;
  int col = g * 64 + wn * 16 + r;
  int tap = cc >> 2, cgi = cc & 3;
  out[o] = f2bf(W1[(size_t)(tap * 128 + cgi * 32 + k) * 256 + col]);
}

// ---- t=0 x conversion: enc fp32 -> padded bf16 [b][66][66][32] (pads pre-zeroed)
__global__ void convert_x0(const float* __restrict__ enc, unsigned short* __restrict__ xb) {
  int idx = blockIdx.x * 256 + threadIdx.x;          // 32768
  int b = idx >> 12, pix = idx & 4095;
  int y = pix >> 6, x = pix & 63;
  const float* s = enc + ((size_t)(b * Tv + 0) * 4096 + pix) * 16;
  float4 f0 = *(const float4*)(s);
  float4 f1 = *(const float4*)(s + 4);
  float4 f2 = *(const float4*)(s + 8);
  float4 f3 = *(const float4*)(s + 12);
  u16x8 o0, o1;
  o0[0]=f2bf(f0.x); o0[1]=f2bf(f0.y); o0[2]=f2bf(f0.z); o0[3]=f2bf(f0.w);
  o0[4]=f2bf(f1.x); o0[5]=f2bf(f1.y); o0[6]=f2bf(f1.z); o0[7]=f2bf(f1.w);
  o1[0]=f2bf(f2.x); o1[1]=f2bf(f2.y); o1[2]=f2bf(f2.z); o1[3]=f2bf(f2.w);
  o1[4]=f2bf(f3.x); o1[5]=f2bf(f3.y); o1[6]=f2bf(f3.z); o1[7]=f2bf(f3.w);
  unsigned short* d = xb + ((size_t)((b * PH + y + 1) * PH) + (x + 1)) * 32;
  *(u16x8*)(d)     = o0;
  *(u16x8*)(d + 8) = o1;
}

// ---- one cell phase: LDS-staged implicit-GEMM (per-wave private 16KB slice,
// counted vmcnt, zero intra-phase barriers) + fused gates; c-state in registers.
// A loads use sc0 (L1 bypass -> always coherent vs intra-XCD L2); W loads cached.
template<int CELL>
__device__ __forceinline__ void cell_phase(
    const char* __restrict__ A0, const char* __restrict__ A1,
    const char* __restrict__ Wr, const float* bi, float (&cst)[4][4],
    unsigned short* __restrict__ hout, float* __restrict__ h1f, float* __restrict__ c1f,
    const unsigned (&offsX)[4], const unsigned (&offsH)[2][4],
    char* slice, int l, int wm, int wn, int r, int kg, int j, int b, int by, int bx)
{
  constexpr int CG = (CELL == 0) ? 3 : 4;
  constexpr int NC = 9 * CG;

  auto ISSUE = [&](int cc, int pp) {
    char* dst = slice + pp * 8192;
    int tap, cgi;
    if (CELL == 0) { tap = cc / 3; cgi = cc - tap * 3; }
    else           { tap = cc >> 2; cgi = cc & 3; }
    int ky = tap / 3, kx = tap - ky * 3;
    const char* srcb;
    unsigned toff;
    if (CELL == 0) {
      if (cgi == 0) { srcb = A0; toff = (unsigned)((ky * PH + kx) * 64); }
      else          { srcb = A1; toff = (unsigned)((ky * PH + kx) * 128); }
    } else {
      srcb = (cgi < 2) ? A0 : A1;
      toff = (unsigned)((ky * PH + kx) * 128);
    }
#pragma unroll
    for (int mi = 0; mi < 4; ++mi) {
      unsigned o = (CELL == 0 && cgi == 0) ? offsX[mi]
                 : offsH[(CELL == 0) ? (cgi - 1) : (cgi & 1)][mi];
      __builtin_amdgcn_global_load_lds((const unsigned int*)(srcb + o + toff),
                                       (unsigned int*)(dst + mi * 1024), 16, 0, 1 /*sc0*/);
    }
    const char* wp = Wr + (size_t)cc * 16384 + wn * 4096 + l * 16;
#pragma unroll
    for (int g = 0; g < 4; ++g)
      __builtin_amdgcn_global_load_lds((const unsigned int*)(wp + g * 1024),
                                       (unsigned int*)(dst + 4096 + g * 1024), 16, 0, 0);
  };

  f32x4 acc[4][4] = {};
  short8 af[2][4], bfv[2][4];

  ISSUE(0, 0);
  ISSUE(1, 1);
#pragma unroll
  for (int cc = 0; cc < NC; ++cc) {
    if (cc == NC - 1) { asm volatile("s_waitcnt vmcnt(0)" ::: "memory"); }
    else              { asm volatile("s_waitcnt vmcnt(8)" ::: "memory"); }
    __builtin_amdgcn_sched_barrier(0);
    const int q = cc & 1;
    const char* src = slice + q * 8192;
#pragma unroll
    for (int mi = 0; mi < 4; ++mi) af[q][mi] = *(const short8*)(src + mi * 1024 + l * 16);
#pragma unroll
    for (int g = 0; g < 4; ++g)  bfv[q][g] = *(const short8*)(src + 4096 + g * 1024 + l * 16);
    if (cc > 0) {
      const int qp = q ^ 1;
#pragma unroll
      for (int mi = 0; mi < 4; ++mi)
#pragma unroll
        for (int g = 0; g < 4; ++g)
          acc[mi][g] = __builtin_amdgcn_mfma_f32_16x16x32_bf16(
              af[qp][mi], bfv[qp][g], acc[mi][g], 0, 0, 0);
    }
    asm volatile("s_waitcnt lgkmcnt(0)" ::: "memory");
    __builtin_amdgcn_sched_barrier(0);
    if (cc + 2 < NC) ISSUE(cc + 2, q);
  }
  {
    const int qp = (NC - 1) & 1;
#pragma unroll
    for (int mi = 0; mi < 4; ++mi)
#pragma unroll
      for (int g = 0; g < 4; ++g)
        acc[mi][g] = __builtin_amdgcn_mfma_f32_16x16x32_bf16(
            af[qp][mi], bfv[qp][g], acc[mi][g], 0, 0, 0);
  }

  // gates: wave owns hid j for all 4 gates; c in registers
#pragma unroll
  for (int mi = 0; mi < 4; ++mi) {
#pragma unroll
    for (int rg = 0; rg < 4; ++rg) {
      int p = wm * 64 + mi * 16 + kg * 4 + rg;       // C/D row = (lane>>4)*4 + reg
      int y = by * 16 + (p >> 3), x = bx * 8 + (p & 7);
      float zi = acc[mi][0][rg] + bi[0];
      float zf = acc[mi][1][rg] + bi[1];
      float zo = acc[mi][2][rg] + bi[2];
      float zg = acc[mi][3][rg] + bi[3];
      float cn = sigmoid_f(zf) * cst[mi][rg] + sigmoid_f(zi) * tanh_f(zg);
      float hn = sigmoid_f(zo) * tanh_f(cn);
      cst[mi][rg] = cn;
      hout[((size_t)((b * PH + y + 1) * PH) + (x + 1)) * HID + j] = f2bf(hn);
      if (CELL == 1 && h1f != nullptr) {
        size_t ci = ((size_t)((b * Hv + y) * Wv) + x) * HID + j;
        h1f[ci] = hn;
        c1f[ci] = cn;
      }
    }
  }
}

// ---- persistent kernel: whole T=16 scan. 256 blocks x 512 thr, 128KB LDS
// => exactly 1 block/CU => exactly 32 blocks/XCD. XCD k owns batch k; all
// cross-block traffic is intra-XCD (own L2), synced by L2-atomic barriers.
__global__ __launch_bounds__(512, 2)
void encoder_persistent(const float* __restrict__ enc, unsigned short* __restrict__ xb,
                        const unsigned short* __restrict__ w0r, const unsigned short* __restrict__ w1r,
                        const float* __restrict__ b0, const float* __restrict__ b1,
                        unsigned short* __restrict__ h0a, unsigned short* __restrict__ h0b,
                        unsigned short* __restrict__ h1a, unsigned short* __restrict__ h1b,
                        float* __restrict__ h1f, float* __restrict__ c1f,
                        unsigned* bar, unsigned* slotctr)
{
  extern __shared__ char lds[];
  const int tid = threadIdx.x;
  const int l = tid & 63, w = tid >> 6;
  const int wm = w >> 2, wn = w & 3;
  const int r = l & 15, kg = l >> 4;
  const int j = wn * 16 + r;

  unsigned xcc;
  asm volatile("s_getreg_b32 %0, hwreg(HW_REG_XCC_ID)" : "=s"(xcc));
  const int xcd = (int)(xcc & 7);

  __shared__ int sh_slot;
  if (tid == 0) sh_slot = (int)atomicAdd(&slotctr[xcd << 5], 1u);
  __syncthreads();
  const int slot = sh_slot;                          // 0..31 within this XCD
  const int b = xcd;                                 // batch owned by this XCD
  const int bx = slot & 7, by = slot >> 3;           // 16x8 px tile
  unsigned* barx = &bar[xcd << 5];

  unsigned offsX[4], offsH[2][4];
#pragma unroll
  for (int mi = 0; mi < 4; ++mi) {
    int p = wm * 64 + mi * 16 + r;
    int y = by * 16 + (p >> 3), x = bx * 8 + (p & 7);
    int pix = (b * PH + y) * PH + x;                 // tap(0,0) in padded coords
    offsX[mi]    = (unsigned)(pix * 64 + kg * 16);
    offsH[0][mi] = (unsigned)(pix * 128 + kg * 16);
    offsH[1][mi] = (unsigned)(pix * 128 + 64 + kg * 16);
  }
  float bi0[4], bi1[4];
#pragma unroll
  for (int g = 0; g < 4; ++g) { bi0[g] = b0[g * 64 + j]; bi1[g] = b1[g * 64 + j]; }

  float c0st[4][4] = {};
  float c1st[4][4] = {};
  char* slice = lds + w * 16384;

  unsigned short* h0buf[2] = {h0a, h0b};
  unsigned short* h1buf[2] = {h1a, h1b};

  unsigned gen = 0;
  auto xbarrier = [&]() {
    __syncthreads();                                 // drains each wave's vmcnt/lgkmcnt
    ++gen;
    if (tid == 0) {
      atomicAdd(barx, 1u);
      const unsigned tgt = gen * 32;
      while (atomicAdd(barx, 0u) < tgt) __builtin_amdgcn_s_sleep(2);
    }
    __syncthreads();
  };

#pragma unroll 1
  for (int t = 0; t < Tv; ++t) {
    const int cur = t & 1, prv = cur ^ 1;
    const bool last = (t == Tv - 1);

    // cell0: conv([x(t), h0(t-1)]) -> h0(t)
    cell_phase<0>((const char*)xb, (const char*)h0buf[prv], (const char*)w0r,
                  bi0, c0st, h0buf[cur], nullptr, nullptr,
                  offsX, offsH, slice, l, wm, wn, r, kg, j, b, by, bx);
    xbarrier();                                      // h0(t) visible intra-XCD

    // cell1: conv([h0(t), h1(t-1)]) -> h1(t) (+ final out at t=15)
    cell_phase<1>((const char*)h0buf[cur], (const char*)h1buf[prv], (const char*)w1r,
                  bi1, c1st, h1buf[cur], last ? h1f : nullptr, last ? c1f : nullptr,
                  offsX, offsH, slice, l, wm, wn, r, kg, j, b, by, bx);

    if (t + 1 < Tv) {
      // convert x(t+1) for this batch (xb re-read only after the barrier)
      int px = slot * 128 + (tid >> 2), q4 = tid & 3;
      int y = px >> 6, x = px & 63;
      const float* s = enc + ((size_t)(b * Tv + (t + 1)) * 4096 + px) * 16 + q4 * 4;
      float4 f = *(const float4*)s;
      unsigned short* d = xb + ((size_t)((b * PH + y + 1) * PH) + (x + 1)) * 32 + q4 * 4;
      d[0] = f2bf(f.x); d[1] = f2bf(f.y); d[2] = f2bf(f.z); d[3] = f2bf(f.w);
      xbarrier();                                    // h1(t) + x(t+1) visible intra-XCD
    }
  }
}

extern "C" void kernel_launch(void* const* d_in, const int* in_sizes, int n_in,
                              void* d_out, int out_size, void* d_ws, size_t ws_size,
                              hipStream_t stream) {
  const float* enc = (const float*)d_in[0];
  const float* W0  = (const float*)d_in[1];
  const float* b0  = (const float*)d_in[2];
  const float* W1  = (const float*)d_in[3];
  const float* b1  = (const float*)d_in[4];

  float* out = (float*)d_out;
  const size_t NST = (size_t)Bv * Hv * Wv * HID;     // 2,097,152
  float* h1f = out;                                   // final h1 (fp32)
  float* c1f = out + NST;                             // final c1 (fp32)

  char* ws = (char*)d_ws;
  const size_t SZ_H = (size_t)Bv * PH * PH * HID * 2; // 4,460,544
  const size_t SZ_X = (size_t)Bv * PH * PH * 32 * 2;  // 2,230,272
  unsigned short* h0a = (unsigned short*)(ws);
  unsigned short* h0b = (unsigned short*)(ws + SZ_H);
  unsigned short* h1a = (unsigned short*)(ws + 2 * SZ_H);
  unsigned short* h1b = (unsigned short*)(ws + 3 * SZ_H);
  unsigned short* xb  = (unsigned short*)(ws + 4 * SZ_H);
  unsigned*       bar     = (unsigned*)(ws + 4 * SZ_H + SZ_X);
  unsigned*       slotctr = (unsigned*)(ws + 4 * SZ_H + SZ_X + 1024);
  unsigned short* w0r = (unsigned short*)(ws + 4 * SZ_H + SZ_X + 2048);
  unsigned short* w1r = (unsigned short*)(ws + 4 * SZ_H + SZ_X + 2048 + (size_t)27 * 16384);

  hipFuncSetAttribute((const void*)encoder_persistent,
                      hipFuncAttributeMaxDynamicSharedMemorySize, 131072);

  // zero: h buffers (t=0 state + halos), x buffer (halos + pad ch), barriers/slots
  hipMemsetAsync(ws, 0, 4 * SZ_H + SZ_X + 2048, stream);

  relayout_w0<<<864, 256, 0, stream>>>(W0, w0r);
  relayout_w1<<<1152, 256, 0, stream>>>(W1, w1r);
  convert_x0<<<128, 256, 0, stream>>>(enc, xb);

  void* args[14] = {(void*)&enc, (void*)&xb, (void*)&w0r, (void*)&w1r,
                    (void*)&b0, (void*)&b1, (void*)&h0a, (void*)&h0b,
                    (void*)&h1a, (void*)&h1b, (void*)&h1f, (void*)&c1f,
                    (void*)&bar, (void*)&slotctr};
  hipLaunchCooperativeKernel(encoder_persistent, dim3(256), dim3(512), args,
                             131072, stream);
}

// Round 7
// 725.104 us; speedup vs baseline: 4.4714x; 4.4714x over previous
//
#include <hip/hip_runtime.h>
#include <hip/hip_bf16.h>

#define Bv 8
#define Tv 16
#define Hv 64
#define Wv 64
#define Cv 16
#define HID 64
#define PH 66   // spatially padded (1-px halo)

typedef short short8 __attribute__((ext_vector_type(8)));
typedef float f32x4 __attribute__((ext_vector_type(4)));
typedef unsigned short u16x8 __attribute__((ext_vector_type(8)));

__device__ __forceinline__ unsigned short f2bf(float x) {
  union { float f; unsigned int u; } v; v.f = x;
  unsigned int r = v.u + 0x7FFF + ((v.u >> 16) & 1);   // RNE
  return (unsigned short)(r >> 16);
}
__device__ __forceinline__ float sigmoid_f(float x) {
  return 1.f / (1.f + __expf(-x));
}
__device__ __forceinline__ float tanh_f(float x) {
  float e = __expf(2.f * x);
  return 1.f - 2.f / (e + 1.f);
}

// ---- weight re-layouts: fp32 [3,3,CI,256] -> bf16 lane-contiguous chunks.
// Chunk cc (16KB): [wn(4)][g(4)][lane(64)][e(8)]; lane l=(kg*16+r) holds
// B[k=kg*8+e][col' = wn*64+g*16+r], orig col = g*64 + wn*16 + r.
__global__ void relayout_w0(const float* __restrict__ W0, unsigned short* __restrict__ out) {
  int o = blockIdx.x * 256 + threadIdx.x;            // 27*8192 = 221184
  if (o >= 27 * 8192) return;
  int cc = o >> 13, t = o & 8191;
  int wn = t >> 11, t2 = t & 2047;
  int g = t2 >> 9, t3 = t2 & 511;
  int l = t3 >> 3, e = t3 & 7;
  int kg = l >> 4, r = l & 15;
  int k = kg * 8 + e;
  int col = g * 64 + wn * 16 + r;
  int tap = cc / 3, cgi = cc - tap * 3;
  int p = cgi * 32 + k;                              // padded ci: 0..15 x, 16..31 pad, 32..95 h
  float v = 0.f;
  if (p < 16)        v = W0[(size_t)(tap * 80 + p) * 256 + col];
  else if (p >= 32)  v = W0[(size_t)(tap * 80 + (p - 16)) * 256 + col];
  out[o] = f2bf(v);
}
__global__ void relayout_w1(const float* __restrict__ W1, unsigned short* __restrict__ out) {
  int o = blockIdx.x * 256 + threadIdx.x;            // 36*8192 = 294912
  if (o >= 36 * 8192) return;
  int cc = o >> 13, t = o & 8191;
  int wn = t >> 11, t2 = t & 2047;
  int g = t2 >> 9, t3 = t2 & 511;
  int l = t3 >> 3, e = t3 & 7;
  int kg = l >> 4, r = l & 15;
  int k = kg * 8 + e;
  int col = g * 64 + wn * 16 + r;
  int tap = cc >> 2, cgi = cc & 3;
  out[o] = f2bf(W1[(size_t)(tap * 128 + cgi * 32 + k) * 256 + col]);
}

// ---- t=0 x conversion: enc fp32 -> padded bf16 [b][66][66][32] (pads pre-zeroed)
__global__ void convert_x0(const float* __restrict__ enc, unsigned short* __restrict__ xb) {
  int idx = blockIdx.x * 256 + threadIdx.x;          // 32768
  int b = idx >> 12, pix = idx & 4095;
  int y = pix >> 6, x = pix & 63;
  const float* s = enc + ((size_t)(b * Tv + 0) * 4096 + pix) * 16;
  float4 f0 = *(const float4*)(s);
  float4 f1 = *(const float4*)(s + 4);
  float4 f2 = *(const float4*)(s + 8);
  float4 f3 = *(const float4*)(s + 12);
  u16x8 o0, o1;
  o0[0]=f2bf(f0.x); o0[1]=f2bf(f0.y); o0[2]=f2bf(f0.z); o0[3]=f2bf(f0.w);
  o0[4]=f2bf(f1.x); o0[5]=f2bf(f1.y); o0[6]=f2bf(f1.z); o0[7]=f2bf(f1.w);
  o1[0]=f2bf(f2.x); o1[1]=f2bf(f2.y); o1[2]=f2bf(f2.z); o1[3]=f2bf(f2.w);
  o1[4]=f2bf(f3.x); o1[5]=f2bf(f3.y); o1[6]=f2bf(f3.z); o1[7]=f2bf(f3.w);
  unsigned short* d = xb + ((size_t)((b * PH + y + 1) * PH) + (x + 1)) * 32;
  *(u16x8*)(d)     = o0;
  *(u16x8*)(d + 8) = o1;
}

// ---- fused ConvLSTM cell step: block-cooperative LDS staging + MFMA + gates.
// Block: 128 px (16x8) x 256 gate-cols, 8 waves. Wave = 64px x 16hid x 4gates.
// Per chunk (K=32): A 8KB staged once (wave w stages px-frag w), W 16KB staged
// once (wave w stages pieces 2w,2w+1). 3 global_load_lds per wave per chunk.
// 5 LDS buffers x 24KB, issue depth 3 (vmcnt(6) counted), 1 raw s_barrier/chunk,
// ds_read pipelined 1 chunk ahead of MFMA (lgkmcnt(8) counted).
template<int CELL>
__global__ __launch_bounds__(512, 2)
void cell_mfma(const unsigned short* __restrict__ A0, const unsigned short* __restrict__ A1,
               const unsigned short* __restrict__ Wr, const float* __restrict__ bias,
               float* __restrict__ cbuf, unsigned short* __restrict__ hout,
               float* __restrict__ h1f, float* __restrict__ c1f,
               const float* __restrict__ enc, int tnext, unsigned short* __restrict__ xnext)
{
  constexpr int CG = (CELL == 0) ? 3 : 4;
  constexpr int NC = 9 * CG;
  extern __shared__ char lds[];                      // 5 x 24KB = 120KB

  const int tid = threadIdx.x;
  const int l = tid & 63, w = tid >> 6;
  const int wm = w >> 2, wn = w & 3;
  const int gid = blockIdx.x;
  const int bx = gid & 7, by = (gid >> 3) & 3, b = gid >> 5;
  const int r = l & 15, kg = l >> 4;
  const int j = wn * 16 + r;

  const char* bases[2] = {(const char*)A0, (const char*)A1};

  // staging source offsets: wave w stages A px-frag w (pixels w*16 + r)
  unsigned offsA[CG];
  {
    int ps = w * 16 + r;
    int ys = by * 16 + (ps >> 3), xs = bx * 8 + (ps & 7);
    int pixs = (b * PH + ys) * PH + xs;              // tap(0,0) in padded coords
#pragma unroll
    for (int cgi = 0; cgi < CG; ++cgi) {
      int chb = (CELL == 0) ? (cgi == 0 ? 64 : 128) : 128;   // bytes per pixel-row
      int cho = (CELL == 0) ? (cgi == 2 ? 64 : 0) : ((cgi & 1) * 64);
      offsA[cgi] = (unsigned)(pixs * chb + cho + kg * 16);
    }
  }

  // ---- early loads (bias + c state), fenced so loop vmcnt counts stay exact
  float bi[4];
#pragma unroll
  for (int g = 0; g < 4; ++g) bi[g] = bias[g * 64 + j];
  float cpre[4][4];
#pragma unroll
  for (int mi = 0; mi < 4; ++mi) {
#pragma unroll
    for (int rg = 0; rg < 4; ++rg) {
      int p = wm * 64 + mi * 16 + kg * 4 + rg;
      int y = by * 16 + (p >> 3), x = bx * 8 + (p & 7);
      cpre[mi][rg] = cbuf[((size_t)((b * Hv + y) * Wv) + x) * HID + j];
    }
  }
  asm volatile("s_waitcnt vmcnt(0)" ::: "memory");
  __builtin_amdgcn_sched_barrier(0);

  auto ISSUE = [&](int cc, int buf) {
    char* dst = lds + buf * 24576;
    int tap, cgi;
    if (CELL == 0) { tap = cc / 3; cgi = cc - tap * 3; }
    else           { tap = cc >> 2; cgi = cc & 3; }
    int ky = tap / 3, kx = tap - ky * 3;
    const char* srcb;
    unsigned toff;
    if (CELL == 0) {
      if (cgi == 0) { srcb = bases[0]; toff = (unsigned)((ky * PH + kx) * 64); }
      else          { srcb = bases[1]; toff = (unsigned)((ky * PH + kx) * 128); }
    } else {
      srcb = bases[cgi >> 1];
      toff = (unsigned)((ky * PH + kx) * 128);
    }
    // A frag w: 1KB (16 px x 64B), LDS layout [kg][r][16B] == lane-linear
    __builtin_amdgcn_global_load_lds((const unsigned int*)(srcb + offsA[cgi] + toff),
                                     (unsigned int*)(dst + w * 1024), 16, 0, 0);
    // W pieces 2w, 2w+1 (identity copy of re-laid-out chunk)
    const char* wp = (const char*)Wr + (size_t)cc * 16384 + (unsigned)(w * 2048 + l * 16);
    __builtin_amdgcn_global_load_lds((const unsigned int*)(wp),
                                     (unsigned int*)(dst + 8192 + w * 2048), 16, 0, 0);
    __builtin_amdgcn_global_load_lds((const unsigned int*)(wp + 1024),
                                     (unsigned int*)(dst + 8192 + w * 2048 + 1024), 16, 0, 0);
  };

  f32x4 acc[4][4] = {};
  short8 af[2][4], bfv[2][4];

  ISSUE(0, 0); ISSUE(1, 1); ISSUE(2, 2);
#pragma unroll
  for (int cc = 0; cc < NC; ++cc) {
    if (cc <= NC - 3)      { asm volatile("s_waitcnt vmcnt(6)" ::: "memory"); }
    else if (cc == NC - 2) { asm volatile("s_waitcnt vmcnt(3)" ::: "memory"); }
    else                   { asm volatile("s_waitcnt vmcnt(0)" ::: "memory"); }
    __builtin_amdgcn_sched_barrier(0);
    __builtin_amdgcn_s_barrier();                    // raw: no compiler vmcnt drain
    __builtin_amdgcn_sched_barrier(0);

    const int q = cc & 1;
    const char* bufp = lds + (cc % 5) * 24576;
#pragma unroll
    for (int mi = 0; mi < 4; ++mi)
      af[q][mi] = *(const short8*)(bufp + (wm * 4 + mi) * 1024 + l * 16);
#pragma unroll
    for (int g = 0; g < 4; ++g)
      bfv[q][g] = *(const short8*)(bufp + 8192 + (wn * 4 + g) * 1024 + l * 16);

    if (cc + 3 < NC) ISSUE(cc + 3, (cc + 3) % 5);

    if (cc > 0) {
      asm volatile("s_waitcnt lgkmcnt(8)" ::: "memory");   // chunk cc-1 reads done
      __builtin_amdgcn_sched_barrier(0);
      const int qp = q ^ 1;
#pragma unroll
      for (int mi = 0; mi < 4; ++mi)
#pragma unroll
        for (int g = 0; g < 4; ++g)
          acc[mi][g] = __builtin_amdgcn_mfma_f32_16x16x32_bf16(
              af[qp][mi], bfv[qp][g], acc[mi][g], 0, 0, 0);
    }
  }
  asm volatile("s_waitcnt lgkmcnt(0)" ::: "memory");
  __builtin_amdgcn_sched_barrier(0);
  {
    const int qp = (NC - 1) & 1;
#pragma unroll
    for (int mi = 0; mi < 4; ++mi)
#pragma unroll
      for (int g = 0; g < 4; ++g)
        acc[mi][g] = __builtin_amdgcn_mfma_f32_16x16x32_bf16(
            af[qp][mi], bfv[qp][g], acc[mi][g], 0, 0, 0);
  }

  // ---- gates: this wave owns hid j for all 4 gates; c from regs
#pragma unroll
  for (int mi = 0; mi < 4; ++mi) {
#pragma unroll
    for (int rg = 0; rg < 4; ++rg) {
      int p = wm * 64 + mi * 16 + kg * 4 + rg;       // C/D row = (lane>>4)*4 + reg
      int y = by * 16 + (p >> 3), x = bx * 8 + (p & 7);
      float zi = acc[mi][0][rg] + bi[0];
      float zf = acc[mi][1][rg] + bi[1];
      float zo = acc[mi][2][rg] + bi[2];
      float zg = acc[mi][3][rg] + bi[3];
      float co = cpre[mi][rg];
      float cn = sigmoid_f(zf) * co + sigmoid_f(zi) * tanh_f(zg);
      float hn = sigmoid_f(zo) * tanh_f(cn);
      size_t ci = ((size_t)((b * Hv + y) * Wv) + x) * HID + j;
      cbuf[ci] = cn;
      hout[((size_t)((b * PH + y + 1) * PH) + (x + 1)) * HID + j] = f2bf(hn);
      if (CELL == 1 && h1f != nullptr) {
        h1f[ci] = hn;
        c1f[ci] = cn;
      }
    }
  }

  // ---- tail: convert x(tnext) for the next cell0 (cell1 only)
  if (CELL == 1 && tnext < Tv) {
    int px = gid * 128 + (tid >> 2), q4 = tid & 3;
    int bb = px >> 12, pix = px & 4095;
    int y = pix >> 6, x = pix & 63;
    const float* s = enc + ((size_t)(bb * Tv + tnext) * 4096 + pix) * 16 + q4 * 4;
    float4 f = *(const float4*)s;
    unsigned short* d = xnext + ((size_t)((bb * PH + y + 1) * PH) + (x + 1)) * 32 + q4 * 4;
    d[0] = f2bf(f.x); d[1] = f2bf(f.y); d[2] = f2bf(f.z); d[3] = f2bf(f.w);
  }
}

extern "C" void kernel_launch(void* const* d_in, const int* in_sizes, int n_in,
                              void* d_out, int out_size, void* d_ws, size_t ws_size,
                              hipStream_t stream) {
  const float* enc = (const float*)d_in[0];
  const float* W0  = (const float*)d_in[1];
  const float* b0  = (const float*)d_in[2];
  const float* W1  = (const float*)d_in[3];
  const float* b1  = (const float*)d_in[4];

  float* out = (float*)d_out;
  const size_t NST = (size_t)Bv * Hv * Wv * HID;     // 2,097,152
  float* h1f = out;                                   // final h1 (fp32)
  float* c1  = out + NST;                             // c1 running state (fp32, in-place)

  char* ws = (char*)d_ws;
  const size_t SZ_C = NST * 4;                        // 8,388,608
  const size_t SZ_H = (size_t)Bv * PH * PH * HID * 2; // 4,460,544
  const size_t SZ_X = (size_t)Bv * PH * PH * 32 * 2;  // 2,230,272
  float*          c0  = (float*)ws;
  unsigned short* h0a = (unsigned short*)(ws + SZ_C);
  unsigned short* h0b = (unsigned short*)(ws + SZ_C + SZ_H);
  unsigned short* h1a = (unsigned short*)(ws + SZ_C + 2 * SZ_H);
  unsigned short* h1b = (unsigned short*)(ws + SZ_C + 3 * SZ_H);
  unsigned short* xb  = (unsigned short*)(ws + SZ_C + 4 * SZ_H);
  unsigned short* w0r = (unsigned short*)(ws + SZ_C + 4 * SZ_H + SZ_X);
  unsigned short* w1r = (unsigned short*)(ws + SZ_C + 4 * SZ_H + SZ_X + (size_t)27 * 16384);

  hipFuncSetAttribute((const void*)cell_mfma<0>, hipFuncAttributeMaxDynamicSharedMemorySize, 131072);
  hipFuncSetAttribute((const void*)cell_mfma<1>, hipFuncAttributeMaxDynamicSharedMemorySize, 131072);

  // zero c0 + h buffers + x buffer (t=0 state, halos, pad channels); zero c1 in d_out
  hipMemsetAsync(ws, 0, SZ_C + 4 * SZ_H + SZ_X, stream);
  hipMemsetAsync(c1, 0, SZ_C, stream);

  relayout_w0<<<864, 256, 0, stream>>>(W0, w0r);
  relayout_w1<<<1152, 256, 0, stream>>>(W1, w1r);
  convert_x0<<<128, 256, 0, stream>>>(enc, xb);

  dim3 grid(256), block(512);
  for (int t = 0; t < Tv; ++t) {
    const bool last = (t == Tv - 1);
    unsigned short* h0r = (t & 1) ? h0b : h0a;
    unsigned short* h0w = (t & 1) ? h0a : h0b;
    unsigned short* h1r = (t & 1) ? h1b : h1a;
    unsigned short* h1w = (t & 1) ? h1a : h1b;
    cell_mfma<0><<<grid, block, 122880, stream>>>(
        xb, h0r, w0r, b0, c0, h0w, nullptr, nullptr, nullptr, Tv, nullptr);
    cell_mfma<1><<<grid, block, 122880, stream>>>(
        h0w, h1r, w1r, b1, c1, h1w, last ? h1f : nullptr, last ? c1 : nullptr,
        enc, t + 1, xb);
  }
}

// Round 8
// 714.827 us; speedup vs baseline: 4.5357x; 1.0144x over previous
//
#include <hip/hip_runtime.h>
#include <hip/hip_bf16.h>

#define Bv 8
#define Tv 16
#define Hv 64
#define Wv 64
#define Cv 16
#define HID 64
#define PH 66   // spatially padded (1-px halo)

typedef short short8 __attribute__((ext_vector_type(8)));
typedef float f32x4 __attribute__((ext_vector_type(4)));
typedef unsigned short u16x8 __attribute__((ext_vector_type(8)));

__device__ __forceinline__ unsigned short f2bf(float x) {
  union { float f; unsigned int u; } v; v.f = x;
  unsigned int r = v.u + 0x7FFF + ((v.u >> 16) & 1);   // RNE
  return (unsigned short)(r >> 16);
}
__device__ __forceinline__ float sigmoid_f(float x) {
  return 1.f / (1.f + __expf(-x));
}
__device__ __forceinline__ float tanh_f(float x) {
  float e = __expf(2.f * x);
  return 1.f - 2.f / (e + 1.f);
}

// ---- weight re-layouts: fp32 [3,3,CI,256] -> bf16 lane-contiguous chunks.
// Chunk cc (16KB): [wn(4)][g(4)][lane(64)][e(8)]; lane l=(kg*16+r) holds
// B[k=kg*8+e][col' = wn*64+g*16+r], orig col = g*64 + wn*16 + r.
__global__ void relayout_w0(const float* __restrict__ W0, unsigned short* __restrict__ out) {
  int o = blockIdx.x * 256 + threadIdx.x;            // 27*8192 = 221184
  if (o >= 27 * 8192) return;
  int cc = o >> 13, t = o & 8191;
  int wn = t >> 11, t2 = t & 2047;
  int g = t2 >> 9, t3 = t2 & 511;
  int l = t3 >> 3, e = t3 & 7;
  int kg = l >> 4, r = l & 15;
  int k = kg * 8 + e;
  int col = g * 64 + wn * 16 + r;
  int tap = cc / 3, cgi = cc - tap * 3;
  int p = cgi * 32 + k;                              // padded ci: 0..15 x, 16..31 pad, 32..95 h
  float v = 0.f;
  if (p < 16)        v = W0[(size_t)(tap * 80 + p) * 256 + col];
  else if (p >= 32)  v = W0[(size_t)(tap * 80 + (p - 16)) * 256 + col];
  out[o] = f2bf(v);
}
__global__ void relayout_w1(const float* __restrict__ W1, unsigned short* __restrict__ out) {
  int o = blockIdx.x * 256 + threadIdx.x;            // 36*8192 = 294912
  if (o >= 36 * 8192) return;
  int cc = o >> 13, t = o & 8191;
  int wn = t >> 11, t2 = t & 2047;
  int g = t2 >> 9, t3 = t2 & 511;
  int l = t3 >> 3, e = t3 & 7;
  int kg = l >> 4, r = l & 15;
  int k = kg * 8 + e;
  int col = g * 64 + wn * 16 + r;
  int tap = cc >> 2, cgi = cc & 3;
  out[o] = f2bf(W1[(size_t)(tap * 128 + cgi * 32 + k) * 256 + col]);
}

// ---- zero only what must be zero per call: x buffer (pads+halo) + h halo rings
__global__ void zero_init(unsigned short* __restrict__ h0a, unsigned short* __restrict__ h0b,
                          unsigned short* __restrict__ h1a, unsigned short* __restrict__ h1b,
                          unsigned short* __restrict__ xb) {
  int idx = blockIdx.x * 256 + threadIdx.x;          // 16B chunks
  u16x8 z = {};
  const int XB_CH = (Bv * PH * PH * 32 * 2) / 16;    // 139392
  if (idx < XB_CH) { *(u16x8*)(xb + idx * 8) = z; return; }
  idx -= XB_CH;
  int bufi = idx / 16640;                            // 8 b x 260 px x 8 chunks
  if (bufi >= 4) return;
  int rem = idx - bufi * 16640;
  int b = rem / 2080, r2 = rem - b * 2080;
  int hp = r2 >> 3, c8 = r2 & 7;
  int y, x;
  if (hp < 66)       { y = 0;  x = hp; }
  else if (hp < 132) { y = 65; x = hp - 66; }
  else { int i2 = hp - 132; y = 1 + (i2 >> 1); x = (i2 & 1) * 65; }
  unsigned short* base = (bufi == 0) ? h0a : (bufi == 1) ? h0b : (bufi == 2) ? h1a : h1b;
  *(u16x8*)(base + ((size_t)((b * PH + y) * PH) + x) * 64 + c8 * 8) = z;
}

// ---- t=0 x conversion: enc fp32 -> padded bf16 [b][66][66][32] (pads pre-zeroed)
__global__ void convert_x0(const float* __restrict__ enc, unsigned short* __restrict__ xb) {
  int idx = blockIdx.x * 256 + threadIdx.x;          // 32768
  int b = idx >> 12, pix = idx & 4095;
  int y = pix >> 6, x = pix & 63;
  const float* s = enc + ((size_t)(b * Tv + 0) * 4096 + pix) * 16;
  float4 f0 = *(const float4*)(s);
  float4 f1 = *(const float4*)(s + 4);
  float4 f2 = *(const float4*)(s + 8);
  float4 f3 = *(const float4*)(s + 12);
  u16x8 o0, o1;
  o0[0]=f2bf(f0.x); o0[1]=f2bf(f0.y); o0[2]=f2bf(f0.z); o0[3]=f2bf(f0.w);
  o0[4]=f2bf(f1.x); o0[5]=f2bf(f1.y); o0[6]=f2bf(f1.z); o0[7]=f2bf(f1.w);
  o1[0]=f2bf(f2.x); o1[1]=f2bf(f2.y); o1[2]=f2bf(f2.z); o1[3]=f2bf(f2.w);
  o1[4]=f2bf(f3.x); o1[5]=f2bf(f3.y); o1[6]=f2bf(f3.z); o1[7]=f2bf(f3.w);
  unsigned short* d = xb + ((size_t)((b * PH + y + 1) * PH) + (x + 1)) * 32;
  *(u16x8*)(d)     = o0;
  *(u16x8*)(d + 8) = o1;
}

// ---- fused ConvLSTM cell step: block-cooperative LDS staging + MFMA + gates.
// Block: 128 px (16x8) x 256 gate-cols, 8 waves. Wave = 64px x 16hid x 4gates.
// Per chunk (K=32): A 8KB staged once (wave w stages px-frag w), W 16KB staged
// once (wave w stages pieces 2w,2w+1). 5 LDS buffers x 24KB, issue depth 4
// (vmcnt(9) counted), 1 raw s_barrier/chunk, ds_read 1 chunk ahead (lgkmcnt(8)).
// T0: t==0 -> h-operand is all-zero: skip its chunks entirely and c_pre = 0.
template<int CELL, bool T0>
__global__ __launch_bounds__(512, 2)
void cell_mfma(const unsigned short* __restrict__ A0, const unsigned short* __restrict__ A1,
               const unsigned short* __restrict__ Wr, const float* __restrict__ bias,
               float* __restrict__ cbuf, unsigned short* __restrict__ hout,
               float* __restrict__ h1f, float* __restrict__ c1f,
               const float* __restrict__ enc, int tnext, unsigned short* __restrict__ xnext)
{
  constexpr int NC = T0 ? (CELL == 0 ? 9 : 18) : (CELL == 0 ? 27 : 36);
  extern __shared__ char lds[];                      // 5 x 24KB = 120KB

  const int tid = threadIdx.x;
  const int l = tid & 63, w = tid >> 6;
  const int wm = w >> 2, wn = w & 3;
  const int gid = blockIdx.x;
  const int bx = gid & 7, by = (gid >> 3) & 3, b = gid >> 5;
  const int r = l & 15, kg = l >> 4;
  const int j = wn * 16 + r;

  const char* bases[2] = {(const char*)A0, (const char*)A1};

  // staging source offsets: wave w stages A px-frag w (pixels w*16 + r)
  int pixs;
  {
    int ps = w * 16 + r;
    int ys = by * 16 + (ps >> 3), xs = bx * 8 + (ps & 7);
    pixs = (b * PH + ys) * PH + xs;                  // tap(0,0) in padded coords
  }

  // ---- early independent loads (bias + c state); overlapped with prologue
  float bi[4];
#pragma unroll
  for (int g = 0; g < 4; ++g) bi[g] = bias[g * 64 + j];
  float cpre[4][4] = {};
  if constexpr (!T0) {
#pragma unroll
    for (int mi = 0; mi < 4; ++mi) {
#pragma unroll
      for (int rg = 0; rg < 4; ++rg) {
        int p = wm * 64 + mi * 16 + kg * 4 + rg;
        int y = by * 16 + (p >> 3), x = bx * 8 + (p & 7);
        cpre[mi][rg] = cbuf[((size_t)((b * Hv + y) * Wv) + x) * HID + j];
      }
    }
  }

  auto ISSUE = [&](int cc, int buf) {
    char* dst = lds + buf * 24576;
    int tap, cgi, wcc;
    if (CELL == 0) {
      if (T0) { tap = cc; cgi = 0; wcc = cc * 3; }
      else    { tap = cc / 3; cgi = cc - tap * 3; wcc = cc; }
    } else {
      if (T0) { tap = cc >> 1; cgi = cc & 1; wcc = tap * 4 + cgi; }
      else    { tap = cc >> 2; cgi = cc & 3; wcc = cc; }
    }
    int ky = tap / 3, kx = tap - ky * 3;
    const char* srcb;
    unsigned aoff;
    if (CELL == 0) {
      if (cgi == 0) { srcb = bases[0]; aoff = (unsigned)((pixs + ky * PH + kx) * 64 + kg * 16); }
      else { srcb = bases[1];
             aoff = (unsigned)((pixs + ky * PH + kx) * 128 + ((cgi == 2) ? 64 : 0) + kg * 16); }
    } else {
      srcb = bases[cgi >> 1];
      aoff = (unsigned)((pixs + ky * PH + kx) * 128 + (cgi & 1) * 64 + kg * 16);
    }
    // A frag w: 1KB (16 px x 64B), LDS layout [kg][r][16B] == lane-linear
    __builtin_amdgcn_global_load_lds((const unsigned int*)(srcb + aoff),
                                     (unsigned int*)(dst + w * 1024), 16, 0, 0);
    // W pieces 2w, 2w+1 (identity copy of re-laid-out chunk)
    const char* wp = (const char*)Wr + (size_t)wcc * 16384 + (unsigned)(w * 2048 + l * 16);
    __builtin_amdgcn_global_load_lds((const unsigned int*)(wp),
                                     (unsigned int*)(dst + 8192 + w * 2048), 16, 0, 0);
    __builtin_amdgcn_global_load_lds((const unsigned int*)(wp + 1024),
                                     (unsigned int*)(dst + 8192 + w * 2048 + 1024), 16, 0, 0);
  };

  f32x4 acc[4][4] = {};
  short8 af[2][4], bfv[2][4];

  ISSUE(0, 0); ISSUE(1, 1); ISSUE(2, 2); ISSUE(3, 3);
#pragma unroll
  for (int cc = 0; cc < NC; ++cc) {
    if (cc <= NC - 4)      { asm volatile("s_waitcnt vmcnt(9)" ::: "memory"); }
    else if (cc == NC - 3) { asm volatile("s_waitcnt vmcnt(6)" ::: "memory"); }
    else if (cc == NC - 2) { asm volatile("s_waitcnt vmcnt(3)" ::: "memory"); }
    else                   { asm volatile("s_waitcnt vmcnt(0)" ::: "memory"); }
    __builtin_amdgcn_sched_barrier(0);
    __builtin_amdgcn_s_barrier();                    // raw: no compiler vmcnt drain
    __builtin_amdgcn_sched_barrier(0);

    const int q = cc & 1;
    const char* bufp = lds + (cc % 5) * 24576;
#pragma unroll
    for (int mi = 0; mi < 4; ++mi)
      af[q][mi] = *(const short8*)(bufp + (wm * 4 + mi) * 1024 + l * 16);
#pragma unroll
    for (int g = 0; g < 4; ++g)
      bfv[q][g] = *(const short8*)(bufp + 8192 + (wn * 4 + g) * 1024 + l * 16);

    if (cc > 0) {
      asm volatile("s_waitcnt lgkmcnt(8)" ::: "memory");   // chunk cc-1 reads done
      __builtin_amdgcn_sched_barrier(0);
    }
    // issue chunk cc+4 only now: it overwrites buf (cc-1)%5, whose ds_reads
    // are proven complete by the lgkmcnt(8) above
    if (cc + 4 < NC) ISSUE(cc + 4, (cc + 4) % 5);
    if (cc > 0) {
      const int qp = q ^ 1;
#pragma unroll
      for (int mi = 0; mi < 4; ++mi)
#pragma unroll
        for (int g = 0; g < 4; ++g)
          acc[mi][g] = __builtin_amdgcn_mfma_f32_16x16x32_bf16(
              af[qp][mi], bfv[qp][g], acc[mi][g], 0, 0, 0);
    }
  }
  asm volatile("s_waitcnt lgkmcnt(0)" ::: "memory");
  __builtin_amdgcn_sched_barrier(0);
  {
    const int qp = (NC - 1) & 1;
#pragma unroll
    for (int mi = 0; mi < 4; ++mi)
#pragma unroll
      for (int g = 0; g < 4; ++g)
        acc[mi][g] = __builtin_amdgcn_mfma_f32_16x16x32_bf16(
            af[qp][mi], bfv[qp][g], acc[mi][g], 0, 0, 0);
  }

  // ---- gates: this wave owns hid j for all 4 gates; c from regs
#pragma unroll
  for (int mi = 0; mi < 4; ++mi) {
#pragma unroll
    for (int rg = 0; rg < 4; ++rg) {
      int p = wm * 64 + mi * 16 + kg * 4 + rg;       // C/D row = (lane>>4)*4 + reg
      int y = by * 16 + (p >> 3), x = bx * 8 + (p & 7);
      float zi = acc[mi][0][rg] + bi[0];
      float zf = acc[mi][1][rg] + bi[1];
      float zo = acc[mi][2][rg] + bi[2];
      float zg = acc[mi][3][rg] + bi[3];
      float co = cpre[mi][rg];
      float cn = sigmoid_f(zf) * co + sigmoid_f(zi) * tanh_f(zg);
      float hn = sigmoid_f(zo) * tanh_f(cn);
      size_t ci = ((size_t)((b * Hv + y) * Wv) + x) * HID + j;
      cbuf[ci] = cn;
      hout[((size_t)((b * PH + y + 1) * PH) + (x + 1)) * HID + j] = f2bf(hn);
      if (CELL == 1 && h1f != nullptr) {
        h1f[ci] = hn;
        c1f[ci] = cn;
      }
    }
  }

  // ---- tail: convert x(tnext) for the next cell0 (cell1 only)
  if (CELL == 1 && tnext < Tv) {
    int px = gid * 128 + (tid >> 2), q4 = tid & 3;
    int bb = px >> 12, pix = px & 4095;
    int y = pix >> 6, x = pix & 63;
    const float* s = enc + ((size_t)(bb * Tv + tnext) * 4096 + pix) * 16 + q4 * 4;
    float4 f = *(const float4*)s;
    unsigned short* d = xnext + ((size_t)((bb * PH + y + 1) * PH) + (x + 1)) * 32 + q4 * 4;
    d[0] = f2bf(f.x); d[1] = f2bf(f.y); d[2] = f2bf(f.z); d[3] = f2bf(f.w);
  }
}

extern "C" void kernel_launch(void* const* d_in, const int* in_sizes, int n_in,
                              void* d_out, int out_size, void* d_ws, size_t ws_size,
                              hipStream_t stream) {
  const float* enc = (const float*)d_in[0];
  const float* W0  = (const float*)d_in[1];
  const float* b0  = (const float*)d_in[2];
  const float* W1  = (const float*)d_in[3];
  const float* b1  = (const float*)d_in[4];

  float* out = (float*)d_out;
  const size_t NST = (size_t)Bv * Hv * Wv * HID;     // 2,097,152
  float* h1f = out;                                   // final h1 (fp32)
  float* c1  = out + NST;                             // c1 running state (fp32, in-place)

  char* ws = (char*)d_ws;
  const size_t SZ_C = NST * 4;                        // 8,388,608
  const size_t SZ_H = (size_t)Bv * PH * PH * HID * 2; // 4,460,544
  const size_t SZ_X = (size_t)Bv * PH * PH * 32 * 2;  // 2,230,272
  float*          c0  = (float*)ws;
  unsigned short* h0a = (unsigned short*)(ws + SZ_C);
  unsigned short* h0b = (unsigned short*)(ws + SZ_C + SZ_H);
  unsigned short* h1a = (unsigned short*)(ws + SZ_C + 2 * SZ_H);
  unsigned short* h1b = (unsigned short*)(ws + SZ_C + 3 * SZ_H);
  unsigned short* xb  = (unsigned short*)(ws + SZ_C + 4 * SZ_H);
  unsigned short* w0r = (unsigned short*)(ws + SZ_C + 4 * SZ_H + SZ_X);
  unsigned short* w1r = (unsigned short*)(ws + SZ_C + 4 * SZ_H + SZ_X + (size_t)27 * 16384);

  hipFuncSetAttribute((const void*)cell_mfma<0,false>, hipFuncAttributeMaxDynamicSharedMemorySize, 131072);
  hipFuncSetAttribute((const void*)cell_mfma<0,true>,  hipFuncAttributeMaxDynamicSharedMemorySize, 131072);
  hipFuncSetAttribute((const void*)cell_mfma<1,false>, hipFuncAttributeMaxDynamicSharedMemorySize, 131072);
  hipFuncSetAttribute((const void*)cell_mfma<1,true>,  hipFuncAttributeMaxDynamicSharedMemorySize, 131072);

  // zero only halos/pads (h state at t=0 handled by T0 chunk-skip; c by T0 c-skip)
  zero_init<<<805, 256, 0, stream>>>(h0a, h0b, h1a, h1b, xb);
  relayout_w0<<<864, 256, 0, stream>>>(W0, w0r);
  relayout_w1<<<1152, 256, 0, stream>>>(W1, w1r);
  convert_x0<<<128, 256, 0, stream>>>(enc, xb);

  dim3 grid(256), block(512);
  for (int t = 0; t < Tv; ++t) {
    const bool last = (t == Tv - 1);
    unsigned short* h0r = (t & 1) ? h0b : h0a;
    unsigned short* h0w = (t & 1) ? h0a : h0b;
    unsigned short* h1r = (t & 1) ? h1b : h1a;
    unsigned short* h1w = (t & 1) ? h1a : h1b;
    if (t == 0) {
      cell_mfma<0,true><<<grid, block, 122880, stream>>>(
          xb, h0r, w0r, b0, c0, h0w, nullptr, nullptr, nullptr, Tv, nullptr);
      cell_mfma<1,true><<<grid, block, 122880, stream>>>(
          h0w, h1r, w1r, b1, c1, h1w, nullptr, nullptr, enc, 1, xb);
    } else {
      cell_mfma<0,false><<<grid, block, 122880, stream>>>(
          xb, h0r, w0r, b0, c0, h0w, nullptr, nullptr, nullptr, Tv, nullptr);
      cell_mfma<1,false><<<grid, block, 122880, stream>>>(
          h0w, h1r, w1r, b1, c1, h1w, last ? h1f : nullptr, last ? c1 : nullptr,
          enc, t + 1, xb);
    }
  }
}